// Round 1
// baseline (1556.899 us; speedup 1.0000x reference)
//
#include <hip/hip_runtime.h>
#include <hip/hip_bf16.h>
#include <math.h>

#define L_SEQ 64
#define NB    128
#define EMBD  512
#define HID   256
#define G4    1024      // 4*HID
#define NCOL  2048      // 2 dirs * 4H
#define DDIM  512       // 2*HID
#define MS    (L_SEQ*NB)  // 8192 rows per sentence

typedef __bf16 bf16_t;
typedef bf16_t bf16x8 __attribute__((ext_vector_type(8)));
typedef float  floatx4 __attribute__((ext_vector_type(4)));
typedef float  floatx8 __attribute__((ext_vector_type(8)));

__device__ __forceinline__ bf16x8 cvt_bf16x8(floatx8 v) {
    bf16x8 r;
    r[0]=(bf16_t)v[0]; r[1]=(bf16_t)v[1]; r[2]=(bf16_t)v[2]; r[3]=(bf16_t)v[3];
    r[4]=(bf16_t)v[4]; r[5]=(bf16_t)v[5]; r[6]=(bf16_t)v[6]; r[7]=(bf16_t)v[7];
    return r;
}

// ---------------------------------------------------------------------------
// Pack Whh (4H,H) row-major into WhhP[dir][k][j] = float4 over gate groups:
// WhhP[((dir*256+k)*256+j)*4 + grp] = Whh_dir[grp*256 + j][k]
// so scan thread j reads one coalesced float4 per k.
// ---------------------------------------------------------------------------
__global__ __launch_bounds__(256) void pack_whh(const float* __restrict__ whh_f,
                                                const float* __restrict__ whh_b,
                                                float* __restrict__ whhP)
{
    int idx = blockIdx.x*256 + threadIdx.x;   // 0 .. 131071 = dr*65536 + k*256 + j
    int dr = idx >> 16;
    int k  = (idx >> 8) & 255;
    int j  = idx & 255;
    const float* whh = dr ? whh_b : whh_f;
    floatx4 v;
    v[0] = whh[          j*256 + k];
    v[1] = whh[ 65536  + j*256 + k];
    v[2] = whh[ 131072 + j*256 + k];
    v[3] = whh[ 196608 + j*256 + k];
    ((floatx4*)whhP)[idx] = v;
}

// ---------------------------------------------------------------------------
// xg GEMM: C[(l,b)][g2] = emb[tok[l,b]] . Wih_dir[g] + (bih+bhh)[g]
// g2 in [0,2048): dir = g2>>10, g = g2&1023. bf16 MFMA 16x16x32, fp32 acc.
// Fragments loaded directly from global (weights L2-hot, emb gathered).
// A-frag: lane holds A[m=lane&15][k=quad*8+j]; B-frag: B[k=quad*8+j][n=lane&15]
// C/D: row=(lane>>4)*4+reg, col=lane&15   (m89/m120-verified layouts)
// ---------------------------------------------------------------------------
__global__ __launch_bounds__(256) void xg_gemm(
    const int*   __restrict__ toks,  const float* __restrict__ emb,
    const float* __restrict__ wih_f, const float* __restrict__ wih_b,
    const float* __restrict__ bih_f, const float* __restrict__ bhh_f,
    const float* __restrict__ bih_b, const float* __restrict__ bhh_b,
    float* __restrict__ xg)
{
    const int tid  = threadIdx.x;
    const int w    = tid >> 6;
    const int lane = tid & 63;
    const int l15  = lane & 15;
    const int quad = lane >> 4;
    const int m0   = blockIdx.y*64 + (w & 1)*32;
    const int n0   = blockIdx.x*64 + (w >> 1)*32;

    const float* aptr[2];
#pragma unroll
    for (int mi = 0; mi < 2; ++mi) {
        int row = m0 + mi*16 + l15;           // row = l*128 + b
        int tok = toks[row];
        aptr[mi] = emb + (long)tok*EMBD + quad*8;
    }
    const float* bptr[2];
    float biasv[2];
    int   g2v[2];
#pragma unroll
    for (int ni = 0; ni < 2; ++ni) {
        int g2   = n0 + ni*16 + l15;
        g2v[ni]  = g2;
        int dir  = g2 >> 10;
        int grow = g2 & 1023;
        const float* wih = dir ? wih_b : wih_f;
        bptr[ni]  = wih + (long)grow*EMBD + quad*8;
        biasv[ni] = dir ? (bih_b[grow] + bhh_b[grow]) : (bih_f[grow] + bhh_f[grow]);
    }

    floatx4 acc[2][2] = {};
    for (int kk = 0; kk < EMBD; kk += 32) {
        bf16x8 a[2], b[2];
#pragma unroll
        for (int mi = 0; mi < 2; ++mi)
            a[mi] = cvt_bf16x8(*(const floatx8*)(aptr[mi] + kk));
#pragma unroll
        for (int ni = 0; ni < 2; ++ni)
            b[ni] = cvt_bf16x8(*(const floatx8*)(bptr[ni] + kk));
#pragma unroll
        for (int mi = 0; mi < 2; ++mi)
#pragma unroll
            for (int ni = 0; ni < 2; ++ni)
                acc[mi][ni] = __builtin_amdgcn_mfma_f32_16x16x32_bf16(
                                  a[mi], b[ni], acc[mi][ni], 0, 0, 0);
    }
#pragma unroll
    for (int mi = 0; mi < 2; ++mi)
#pragma unroll
        for (int ni = 0; ni < 2; ++ni)
#pragma unroll
            for (int r = 0; r < 4; ++r) {
                int m = m0 + mi*16 + quad*4 + r;
                xg[(long)m*NCOL + g2v[ni]] = acc[mi][ni][r] + biasv[ni];
            }
}

// ---------------------------------------------------------------------------
// LSTM scan. Grid (32, 2*npairs): blockIdx.y -> (pair, dir); blockIdx.x -> 4-batch chunk.
// h (4x256) in LDS, c in regs; gates: acc[b][grp] = sum_k WhhP[dir][k][j].grp * h[b][k]
// Backward dir consumes original time index lt = 63-t and writes o[lt] (= hb[::-1]).
// ---------------------------------------------------------------------------
__global__ __launch_bounds__(256) void lstm_scan(
    const float* __restrict__ xgA, float* __restrict__ oA,
    const float* __restrict__ xgB, float* __restrict__ oB,
    const float* __restrict__ whhP)
{
    const int tid  = threadIdx.x;          // j = hidden index 0..255
    const int pair = blockIdx.y >> 1;
    const int dr   = blockIdx.y & 1;
    const int b0   = blockIdx.x * 4;
    const float* xg = pair ? xgB : xgA;
    float*       o  = pair ? oB  : oA;

    __shared__ float h[4][HID];
#pragma unroll
    for (int b = 0; b < 4; ++b) h[b][tid] = 0.0f;
    float c[4] = {0.0f, 0.0f, 0.0f, 0.0f};
    __syncthreads();

    const floatx4* wp = (const floatx4*)whhP + (long)dr*65536 + tid;

    for (int t = 0; t < L_SEQ; ++t) {
        const int lt = dr ? (L_SEQ-1-t) : t;

        float acc[4][4];
#pragma unroll
        for (int b = 0; b < 4; ++b)
#pragma unroll
            for (int g = 0; g < 4; ++g) acc[b][g] = 0.0f;

#pragma unroll 8
        for (int k = 0; k < HID; ++k) {
            floatx4 wv = wp[(long)k*256];
            float h0 = h[0][k], h1 = h[1][k], h2 = h[2][k], h3 = h[3][k];
#pragma unroll
            for (int g = 0; g < 4; ++g) {
                acc[0][g] += wv[g]*h0;
                acc[1][g] += wv[g]*h1;
                acc[2][g] += wv[g]*h2;
                acc[3][g] += wv[g]*h3;
            }
        }

        float hn[4];
#pragma unroll
        for (int b = 0; b < 4; ++b) {
            long base = ((long)lt*NB + b0 + b)*NCOL + dr*G4 + tid;
            float gi = acc[b][0] + xg[base];
            float gf = acc[b][1] + xg[base + 256];
            float gg = acc[b][2] + xg[base + 512];
            float go = acc[b][3] + xg[base + 768];
            float iv = 1.0f/(1.0f + expf(-gi));
            float fv = 1.0f/(1.0f + expf(-gf));
            float gv = tanhf(gg);
            float ov = 1.0f/(1.0f + expf(-go));
            c[b]  = fv*c[b] + iv*gv;
            hn[b] = ov*tanhf(c[b]);
            o[((long)lt*NB + b0 + b)*DDIM + dr*HID + tid] = hn[b];
        }
        __syncthreads();
#pragma unroll
        for (int b = 0; b < 4; ++b) h[b][tid] = hn[b];
        __syncthreads();
    }
}

// ---------------------------------------------------------------------------
// mp1[b,d] = max_l o1[l,b,d]
// ---------------------------------------------------------------------------
__global__ __launch_bounds__(256) void k_mp1(const float* __restrict__ o1,
                                             float* __restrict__ mp1)
{
    int gid = blockIdx.x*256 + threadIdx.x;   // b*512 + d
    float m = -3.402823466e+38f;
    for (int l = 0; l < L_SEQ; ++l)
        m = fmaxf(m, o1[(long)l*(NB*DDIM) + gid]);
    mp1[gid] = m;
}

// ---------------------------------------------------------------------------
// att (raw-reshape (B,D,L) view of o2), softmax over L, new_pool (raw (B,L,D)
// view), sim[b] = exp(-sum_d |mp1-new_pool|). One block per b.
// ---------------------------------------------------------------------------
__global__ __launch_bounds__(256) void k_att(const float* __restrict__ o2,
                                             const float* __restrict__ mp1,
                                             float* __restrict__ sim)
{
    const int b   = blockIdx.x;
    const int tid = threadIdx.x;
    const int l   = tid & 63;
    const int cp  = tid >> 6;
    __shared__ float spart[256];
    __shared__ float satt[64], sexp[64], ssm[64];
    __shared__ float red[256];

    const float* o2b = o2  + (long)b*32768;   // b*D*L == b*L*D
    const float* mpb = mp1 + b*DDIM;

    float p = 0.0f;
    for (int d = cp*128; d < cp*128 + 128; ++d)
        p += mpb[d] * o2b[d*64 + l];          // (B,D,L) raw view
    spart[tid] = p;
    __syncthreads();
    if (tid < 64)
        satt[tid] = spart[tid] + spart[tid+64] + spart[tid+128] + spart[tid+192];
    __syncthreads();
    if (tid < 64) {
        float mx = satt[0];
        for (int i = 1; i < 64; ++i) mx = fmaxf(mx, satt[i]);
        sexp[tid] = expf(satt[tid] - mx);
    }
    __syncthreads();
    if (tid < 64) {
        float s = 0.0f;
        for (int i = 0; i < 64; ++i) s += sexp[i];
        ssm[tid] = sexp[tid] / s;
    }
    __syncthreads();

    float np0 = 0.0f, np1 = 0.0f;
    for (int l2 = 0; l2 < 64; ++l2) {
        float smv = ssm[l2];
        np0 += smv * o2b[l2*DDIM + tid];       // (B,L,D) raw view
        np1 += smv * o2b[l2*DDIM + tid + 256];
    }
    float diff = fabsf(mpb[tid] - np0) + fabsf(mpb[tid+256] - np1);
    red[tid] = diff;
    __syncthreads();
    for (int s = 128; s > 0; s >>= 1) {
        if (tid < s) red[tid] += red[tid + s];
        __syncthreads();
    }
    if (tid == 0) sim[b] = expf(-red[0]);
}

// ---------------------------------------------------------------------------
// commonWords + masked maxes. d[i] = last j with s1[j]==s2[i] else -1;
// mask = (d>1) & (s2>0); e1h = max_i(masked) o1[pos[i],b,:], e2h over o2[i,b,:].
// ---------------------------------------------------------------------------
__global__ __launch_bounds__(256) void k_common(
    const int*   __restrict__ t1, const int* __restrict__ t2,
    const float* __restrict__ o1, const float* __restrict__ o2,
    float* __restrict__ e1h, float* __restrict__ e2h)
{
    const int b   = blockIdx.x;
    const int tid = threadIdx.x;
    __shared__ int ss1[64];
    __shared__ int smask[64];
    __shared__ int spos[64];
    __shared__ int sany;
    if (tid == 0) sany = 0;
    if (tid < 64) ss1[tid] = t1[tid*NB + b];
    __syncthreads();
    if (tid < 64) {
        int s2 = t2[tid*NB + b];
        int dmax = -1;
        for (int j = 0; j < 64; ++j)
            if (ss1[j] == s2) dmax = j;
        int mk = (dmax > 1) && (s2 > 0);
        smask[tid] = mk;
        spos[tid]  = dmax < 0 ? 0 : dmax;     // clip(d,0,63)
        if (mk) sany = 1;                      // benign race
    }
    __syncthreads();
    int has = sany;
#pragma unroll
    for (int half = 0; half < 2; ++half) {
        int dd = tid + half*256;
        float m1 = -3.402823466e+38f, m2 = -3.402823466e+38f;
        for (int i = 0; i < 64; ++i) {
            if (smask[i]) {
                m1 = fmaxf(m1, o1[(long)spos[i]*(NB*DDIM) + b*DDIM + dd]);
                m2 = fmaxf(m2, o2[(long)i      *(NB*DDIM) + b*DDIM + dd]);
            }
        }
        e1h[b*DDIM + dd] = has ? m1 : 0.0f;
        e2h[b*DDIM + dd] = has ? m2 : 0.0f;
    }
}

// ---------------------------------------------------------------------------
extern "C" void kernel_launch(void* const* d_in, const int* in_sizes, int n_in,
                              void* d_out, int out_size, void* d_ws, size_t ws_size,
                              hipStream_t stream)
{
    (void)in_sizes; (void)n_in; (void)out_size;
    const int*   t1    = (const int*)d_in[0];
    const int*   t2    = (const int*)d_in[1];
    const float* emb   = (const float*)d_in[2];
    const float* wih_f = (const float*)d_in[3];
    const float* whh_f = (const float*)d_in[4];
    const float* bih_f = (const float*)d_in[5];
    const float* bhh_f = (const float*)d_in[6];
    const float* wih_b = (const float*)d_in[7];
    const float* whh_b = (const float*)d_in[8];
    const float* bih_b = (const float*)d_in[9];
    const float* bhh_b = (const float*)d_in[10];
    float* out = (float*)d_out;

    char* ws = (char*)d_ws;
    size_t off = 0;
    auto carve = [&](size_t bytes) -> void* {
        void* p = ws + off;
        off = (off + bytes + 255) & ~(size_t)255;
        return p;
    };
    float* o1   = (float*)carve(sizeof(float)*(size_t)L_SEQ*NB*DDIM);
    float* o2   = (float*)carve(sizeof(float)*(size_t)L_SEQ*NB*DDIM);
    float* whhP = (float*)carve(sizeof(float)*2*HID*G4);
    float* mp1  = (float*)carve(sizeof(float)*NB*DDIM);
    size_t xg_one = sizeof(float)*(size_t)MS*NCOL;     // 67.1 MB per sentence
    bool p0 = (off + 2*xg_one) <= ws_size;             // 170 MB total path
    float* xg0 = (float*)carve(xg_one);
    float* xg1 = p0 ? (float*)carve(xg_one) : xg0;

    hipLaunchKernelGGL(pack_whh, dim3(512), dim3(256), 0, stream, whh_f, whh_b, whhP);

    dim3 ggrid(32, 128);   // N-blocks x M-blocks (2048/64, 8192/64)
    if (p0) {
        hipLaunchKernelGGL(xg_gemm, ggrid, dim3(256), 0, stream,
                           t1, emb, wih_f, wih_b, bih_f, bhh_f, bih_b, bhh_b, xg0);
        hipLaunchKernelGGL(xg_gemm, ggrid, dim3(256), 0, stream,
                           t2, emb, wih_f, wih_b, bih_f, bhh_f, bih_b, bhh_b, xg1);
        hipLaunchKernelGGL(lstm_scan, dim3(32, 4), dim3(256), 0, stream,
                           xg0, o1, xg1, o2, whhP);
    } else {
        hipLaunchKernelGGL(xg_gemm, ggrid, dim3(256), 0, stream,
                           t1, emb, wih_f, wih_b, bih_f, bhh_f, bih_b, bhh_b, xg0);
        hipLaunchKernelGGL(lstm_scan, dim3(32, 2), dim3(256), 0, stream,
                           xg0, o1, xg0, o1, whhP);
        hipLaunchKernelGGL(xg_gemm, ggrid, dim3(256), 0, stream,
                           t2, emb, wih_f, wih_b, bih_f, bhh_f, bih_b, bhh_b, xg0);
        hipLaunchKernelGGL(lstm_scan, dim3(32, 2), dim3(256), 0, stream,
                           xg0, o2, xg0, o2, whhP);
    }

    hipLaunchKernelGGL(k_mp1, dim3(256), dim3(256), 0, stream, o1, mp1);
    hipLaunchKernelGGL(k_att, dim3(128), dim3(256), 0, stream, o2, mp1, out);
    hipLaunchKernelGGL(k_common, dim3(128), dim3(256), 0, stream,
                       t1, t2, o1, o2, out + NB, out + NB + NB*DDIM);
}

// Round 2
// 774.997 us; speedup vs baseline: 2.0089x; 2.0089x over previous
//
#include <hip/hip_runtime.h>
#include <hip/hip_bf16.h>
#include <math.h>

#define L_SEQ 64
#define NB    128
#define EMBD  512
#define HID   256
#define G4    1024      // 4*HID
#define NCOL  2048      // 2 dirs * 4H
#define DDIM  512       // 2*HID
#define MS    (L_SEQ*NB)   // 8192 rows per sentence
#define MTOT  (2*MS)       // 16384 combined rows
#define HSTR  260          // padded hbuf row stride (floats): even LDS bank spread

typedef __bf16 bf16_t;
typedef bf16_t bf16x8 __attribute__((ext_vector_type(8)));
typedef float  floatx4 __attribute__((ext_vector_type(4)));
typedef float  floatx8 __attribute__((ext_vector_type(8)));

__device__ __forceinline__ bf16x8 cvt_bf16x8(floatx8 v) {
    bf16x8 r;
    r[0]=(bf16_t)v[0]; r[1]=(bf16_t)v[1]; r[2]=(bf16_t)v[2]; r[3]=(bf16_t)v[3];
    r[4]=(bf16_t)v[4]; r[5]=(bf16_t)v[5]; r[6]=(bf16_t)v[6]; r[7]=(bf16_t)v[7];
    return r;
}

__device__ __forceinline__ void gload_lds16(const bf16_t* g, bf16_t* l) {
    __builtin_amdgcn_global_load_lds(
        (const __attribute__((address_space(1))) unsigned int*)(g),
        (__attribute__((address_space(3))) unsigned int*)(l), 16, 0, 0);
}

__device__ __forceinline__ float fsigmoid(float x) {
    return __builtin_amdgcn_rcpf(1.0f + __expf(-x));
}
__device__ __forceinline__ float ftanh(float x) {
    // tanh(x) = 1 - 2/(exp(2x)+1)
    return 1.0f - 2.0f * __builtin_amdgcn_rcpf(__expf(2.0f*x) + 1.0f);
}

// ---------------------------------------------------------------------------
// Pack kernels: bf16 A (emb gather, both sentences), bf16 B (wih), bf16 whh,
// bias. All trivially memory-bound.
// ---------------------------------------------------------------------------
__global__ __launch_bounds__(256) void k_pack_a(const int* __restrict__ t1,
                                                const int* __restrict__ t2,
                                                const float* __restrict__ emb,
                                                bf16_t* __restrict__ A)
{
    int gid = blockIdx.x*256 + threadIdx.x;     // MTOT*512/8 = 1048576 threads
    int row = gid >> 6;
    int k8  = (gid & 63) * 8;
    int tok = (row < MS) ? t1[row] : t2[row - MS];
    floatx8 v = *(const floatx8*)(emb + (size_t)tok*EMBD + k8);
    *(bf16x8*)(A + (size_t)row*EMBD + k8) = cvt_bf16x8(v);
}

__global__ __launch_bounds__(256) void k_pack_b(const float* __restrict__ wih_f,
                                                const float* __restrict__ wih_b,
                                                bf16_t* __restrict__ B)
{
    int gid = blockIdx.x*256 + threadIdx.x;     // 2048*512/8 = 131072 threads
    int n   = gid >> 6;
    int k8  = (gid & 63) * 8;
    const float* src = (n >= 1024) ? (wih_b + (size_t)(n-1024)*EMBD)
                                   : (wih_f + (size_t)n*EMBD);
    *(bf16x8*)(B + (size_t)n*EMBD + k8) = cvt_bf16x8(*(const floatx8*)(src + k8));
}

__global__ __launch_bounds__(256) void k_pack_whh(const float* __restrict__ whh_f,
                                                  const float* __restrict__ whh_b,
                                                  bf16_t* __restrict__ whhB)
{
    int gid = blockIdx.x*256 + threadIdx.x;     // 2*1024*256/8 = 65536 threads
    int r2  = gid >> 5;                         // 0..2047 = dir*1024 + n
    int k8  = (gid & 31) * 8;
    const float* src = (r2 >= 1024) ? (whh_b + (size_t)(r2-1024)*HID)
                                    : (whh_f + (size_t)r2*HID);
    *(bf16x8*)(whhB + (size_t)r2*HID + k8) = cvt_bf16x8(*(const floatx8*)(src + k8));
}

__global__ __launch_bounds__(256) void k_pack_bias(const float* __restrict__ bih_f,
                                                   const float* __restrict__ bhh_f,
                                                   const float* __restrict__ bih_b,
                                                   const float* __restrict__ bhh_b,
                                                   float* __restrict__ bias)
{
    int n = blockIdx.x*256 + threadIdx.x;       // 2048
    bias[n] = (n >= 1024) ? (bih_b[n-1024] + bhh_b[n-1024])
                          : (bih_f[n] + bhh_f[n]);
}

// ---------------------------------------------------------------------------
// xg GEMM (m97-style): C[m][n] = A[m][:].B[n][:] + bias[n]
// M=16384, N=2048, K=512, bf16 inputs, fp32 out. 128x128 tile, BK=32,
// global_load_lds width-16 staging, 4 waves each 64x64 quadrant.
// ---------------------------------------------------------------------------
__global__ __launch_bounds__(256) void xg_gemm2(const bf16_t* __restrict__ A,
                                                const bf16_t* __restrict__ B,
                                                const float* __restrict__ bias,
                                                float* __restrict__ xg)
{
    __shared__ bf16_t As[128*32];
    __shared__ bf16_t Bs[128*32];
    const int tid  = threadIdx.x;
    const int wid  = tid >> 6;
    const int lane = tid & 63;
    const int l15  = lane & 15;
    const int quad = lane >> 4;
    const int m0   = blockIdx.y * 128;
    const int n0   = blockIdx.x * 128;
    const int mw   = (wid & 1) * 64;
    const int nw   = (wid >> 1) * 64;

    float biasv[4];
#pragma unroll
    for (int ni = 0; ni < 4; ++ni) biasv[ni] = bias[n0 + nw + ni*16 + l15];

    const int srow = tid >> 2;          // 0..63
    const int sk8  = (tid & 3) * 8;

    floatx4 acc[4][4] = {};
    for (int kk = 0; kk < EMBD; kk += 32) {
#pragma unroll
        for (int inst = 0; inst < 2; ++inst) {
            gload_lds16(A + (size_t)(m0 + inst*64 + srow)*EMBD + kk + sk8,
                        As + inst*2048 + wid*512);
            gload_lds16(B + (size_t)(n0 + inst*64 + srow)*EMBD + kk + sk8,
                        Bs + inst*2048 + wid*512);
        }
        __syncthreads();
        bf16x8 a[4], b[4];
#pragma unroll
        for (int mi = 0; mi < 4; ++mi)
            a[mi] = *(const bf16x8*)(As + (mw + mi*16 + l15)*32 + quad*8);
#pragma unroll
        for (int ni = 0; ni < 4; ++ni)
            b[ni] = *(const bf16x8*)(Bs + (nw + ni*16 + l15)*32 + quad*8);
#pragma unroll
        for (int mi = 0; mi < 4; ++mi)
#pragma unroll
            for (int ni = 0; ni < 4; ++ni)
                acc[mi][ni] = __builtin_amdgcn_mfma_f32_16x16x32_bf16(
                                  a[mi], b[ni], acc[mi][ni], 0, 0, 0);
        __syncthreads();
    }
#pragma unroll
    for (int mi = 0; mi < 4; ++mi)
#pragma unroll
        for (int ni = 0; ni < 4; ++ni)
#pragma unroll
            for (int r = 0; r < 4; ++r) {
                int m = m0 + mw + mi*16 + quad*4 + r;
                int n = n0 + nw + ni*16 + l15;
                xg[(size_t)m*NCOL + n] = acc[mi][ni][r] + biasv[ni];
            }
}

// ---------------------------------------------------------------------------
// LSTM scan, MFMA version. Combined batch 256 (2 sentences share weights).
// Grid (16,2): x = 16-batch chunk of combined 256, y = dir. 512 threads.
// Wave w owns gate columns j in [w*32, w*32+32) for all 4 gates.
// B-frags: whhB[dir][col][k] bf16; 24 frags (grp<3, s=0) cached in VGPRs,
// 40 streamed per step from L2. h fp32 in LDS (ping-pong, stride 260).
// xg for the step prefetched to 32 regs at step start (hides HBM latency).
// ---------------------------------------------------------------------------
__global__ __launch_bounds__(512, 2) void lstm_scan2(
    const bf16_t* __restrict__ whhB,   // [2][1024][256]
    const float*  __restrict__ xg,     // [2*8192][2048]
    float* __restrict__ o1, float* __restrict__ o2)
{
    const int tid  = threadIdx.x;
    const int wid  = tid >> 6;
    const int lane = tid & 63;
    const int l15  = lane & 15;
    const int quad = lane >> 4;
    const int bc   = blockIdx.x;          // 0..15 combined-batch chunk
    const int dr   = blockIdx.y;          // 0..1
    const int sent = bc >> 3;
    const int bloc0 = (bc & 7) * 16;      // local batch base within sentence
    float* o = sent ? o2 : o1;
    const float* xgs = xg + (size_t)sent * MS * NCOL;

    __shared__ float hbuf[2][16][HSTR];   // 33,280 B
    for (int i = tid; i < 2*16*HSTR; i += 512) ((float*)hbuf)[i] = 0.0f;
    __syncthreads();

    const bf16_t* bbase = whhB + (size_t)dr*1024*HID;
    // cached B-frags: grp 0..2, s=0
    bf16x8 bw[3][8];
#pragma unroll
    for (int grp = 0; grp < 3; ++grp) {
        const bf16_t* cg = bbase + (size_t)(grp*256 + wid*32 + l15)*HID + quad*8;
#pragma unroll
        for (int ks = 0; ks < 8; ++ks)
            bw[grp][ks] = *(const bf16x8*)(cg + ks*32);
    }
    // streamed bases: grp3-s0 and grp0..3-s1
    const bf16_t* sg3 = bbase + (size_t)(3*256 + wid*32 + l15)*HID + quad*8;
    const bf16_t* ss[4];
#pragma unroll
    for (int grp = 0; grp < 4; ++grp)
        ss[grp] = bbase + (size_t)(grp*256 + wid*32 + 16 + l15)*HID + quad*8;

    float cst[2][4] = {};
    int pp = 0;

    for (int t = 0; t < L_SEQ; ++t) {
        const int lt = dr ? (L_SEQ-1-t) : t;

        // prefetch xg for this step into registers (coalesced 64B segments)
        float xgv[4][2][4];
#pragma unroll
        for (int grp = 0; grp < 4; ++grp)
#pragma unroll
            for (int s = 0; s < 2; ++s)
#pragma unroll
                for (int r = 0; r < 4; ++r)
                    xgv[grp][s][r] = xgs[(size_t)(lt*NB + bloc0 + quad*4 + r)*NCOL
                                         + dr*G4 + grp*256 + wid*32 + s*16 + l15];

        // A-frags from hbuf[pp]
        bf16x8 af[8];
        {
            const float* hb = &hbuf[pp][0][0] + l15*HSTR + quad*8;
#pragma unroll
            for (int ks = 0; ks < 8; ++ks) {
                floatx4 lo = *(const floatx4*)(hb + ks*32);
                floatx4 hi = *(const floatx4*)(hb + ks*32 + 4);
                bf16x8 a;
#pragma unroll
                for (int i = 0; i < 4; ++i) { a[i] = (bf16_t)lo[i]; a[4+i] = (bf16_t)hi[i]; }
                af[ks] = a;
            }
        }

        floatx4 acc[4][2] = {};
#pragma unroll
        for (int ks = 0; ks < 8; ++ks) {
            bf16x8 b3  = *(const bf16x8*)(sg3 + ks*32);
            bf16x8 b1[4];
#pragma unroll
            for (int grp = 0; grp < 4; ++grp)
                b1[grp] = *(const bf16x8*)(ss[grp] + ks*32);
#pragma unroll
            for (int grp = 0; grp < 3; ++grp)
                acc[grp][0] = __builtin_amdgcn_mfma_f32_16x16x32_bf16(
                                  af[ks], bw[grp][ks], acc[grp][0], 0, 0, 0);
            acc[3][0] = __builtin_amdgcn_mfma_f32_16x16x32_bf16(
                                  af[ks], b3, acc[3][0], 0, 0, 0);
#pragma unroll
            for (int grp = 0; grp < 4; ++grp)
                acc[grp][1] = __builtin_amdgcn_mfma_f32_16x16x32_bf16(
                                  af[ks], b1[grp], acc[grp][1], 0, 0, 0);
        }

        __syncthreads();   // hbuf[pp] reads done; (no xg-LDS now, kept for WAR)

        // epilogue: gates -> c,h ; write o and hbuf[pp^1]
#pragma unroll
        for (int s = 0; s < 2; ++s) {
            const int j = wid*32 + s*16 + l15;
#pragma unroll
            for (int r = 0; r < 4; ++r) {
                const int m = quad*4 + r;
                float gi = acc[0][s][r] + xgv[0][s][r];
                float gf = acc[1][s][r] + xgv[1][s][r];
                float gg = acc[2][s][r] + xgv[2][s][r];
                float go = acc[3][s][r] + xgv[3][s][r];
                float cv = fsigmoid(gf)*cst[s][r] + fsigmoid(gi)*ftanh(gg);
                cst[s][r] = cv;
                float hv = fsigmoid(go)*ftanh(cv);
                o[(size_t)(lt*NB + bloc0 + m)*DDIM + dr*HID + j] = hv;
                hbuf[pp^1][m][j] = hv;
            }
        }
        __syncthreads();
        pp ^= 1;
    }
}

// ---------------------------------------------------------------------------
// mp1[b,d] = max_l o1[l,b,d]
// ---------------------------------------------------------------------------
__global__ __launch_bounds__(256) void k_mp1(const float* __restrict__ o1,
                                             float* __restrict__ mp1)
{
    int gid = blockIdx.x*256 + threadIdx.x;   // b*512 + d
    float m = -3.402823466e+38f;
    for (int l = 0; l < L_SEQ; ++l)
        m = fmaxf(m, o1[(size_t)l*(NB*DDIM) + gid]);
    mp1[gid] = m;
}

// ---------------------------------------------------------------------------
// att (raw (B,D,L) view of o2), softmax over L, new_pool (raw (B,L,D) view),
// sim[b] = exp(-sum_d |mp1-new_pool|). One block per b.
// ---------------------------------------------------------------------------
__global__ __launch_bounds__(256) void k_att(const float* __restrict__ o2,
                                             const float* __restrict__ mp1,
                                             float* __restrict__ sim)
{
    const int b   = blockIdx.x;
    const int tid = threadIdx.x;
    const int l   = tid & 63;
    const int cp  = tid >> 6;
    __shared__ float spart[256];
    __shared__ float satt[64], sexp[64], ssm[64];
    __shared__ float red[256];

    const float* o2b = o2  + (size_t)b*32768;
    const float* mpb = mp1 + b*DDIM;

    float p = 0.0f;
    for (int d = cp*128; d < cp*128 + 128; ++d)
        p += mpb[d] * o2b[d*64 + l];
    spart[tid] = p;
    __syncthreads();
    if (tid < 64)
        satt[tid] = spart[tid] + spart[tid+64] + spart[tid+128] + spart[tid+192];
    __syncthreads();
    if (tid < 64) {
        float mx = satt[0];
        for (int i = 1; i < 64; ++i) mx = fmaxf(mx, satt[i]);
        sexp[tid] = expf(satt[tid] - mx);
    }
    __syncthreads();
    if (tid < 64) {
        float s = 0.0f;
        for (int i = 0; i < 64; ++i) s += sexp[i];
        ssm[tid] = sexp[tid] / s;
    }
    __syncthreads();

    float np0 = 0.0f, np1 = 0.0f;
    for (int l2 = 0; l2 < 64; ++l2) {
        float smv = ssm[l2];
        np0 += smv * o2b[l2*DDIM + tid];
        np1 += smv * o2b[l2*DDIM + tid + 256];
    }
    float diff = fabsf(mpb[tid] - np0) + fabsf(mpb[tid+256] - np1);
    red[tid] = diff;
    __syncthreads();
    for (int s = 128; s > 0; s >>= 1) {
        if (tid < s) red[tid] += red[tid + s];
        __syncthreads();
    }
    if (tid == 0) sim[b] = expf(-red[0]);
}

// ---------------------------------------------------------------------------
// commonWords + masked maxes.
// ---------------------------------------------------------------------------
__global__ __launch_bounds__(256) void k_common(
    const int*   __restrict__ t1, const int* __restrict__ t2,
    const float* __restrict__ o1, const float* __restrict__ o2,
    float* __restrict__ e1h, float* __restrict__ e2h)
{
    const int b   = blockIdx.x;
    const int tid = threadIdx.x;
    __shared__ int ss1[64];
    __shared__ int smask[64];
    __shared__ int spos[64];
    __shared__ int sany;
    if (tid == 0) sany = 0;
    if (tid < 64) ss1[tid] = t1[tid*NB + b];
    __syncthreads();
    if (tid < 64) {
        int s2 = t2[tid*NB + b];
        int dmax = -1;
        for (int j = 0; j < 64; ++j)
            if (ss1[j] == s2) dmax = j;
        int mk = (dmax > 1) && (s2 > 0);
        smask[tid] = mk;
        spos[tid]  = dmax < 0 ? 0 : dmax;
        if (mk) sany = 1;
    }
    __syncthreads();
    int has = sany;
#pragma unroll
    for (int half = 0; half < 2; ++half) {
        int dd = tid + half*256;
        float m1 = -3.402823466e+38f, m2 = -3.402823466e+38f;
        for (int i = 0; i < 64; ++i) {
            if (smask[i]) {
                m1 = fmaxf(m1, o1[(size_t)spos[i]*(NB*DDIM) + b*DDIM + dd]);
                m2 = fmaxf(m2, o2[(size_t)i      *(NB*DDIM) + b*DDIM + dd]);
            }
        }
        e1h[b*DDIM + dd] = has ? m1 : 0.0f;
        e2h[b*DDIM + dd] = has ? m2 : 0.0f;
    }
}

// ---------------------------------------------------------------------------
extern "C" void kernel_launch(void* const* d_in, const int* in_sizes, int n_in,
                              void* d_out, int out_size, void* d_ws, size_t ws_size,
                              hipStream_t stream)
{
    (void)in_sizes; (void)n_in; (void)out_size; (void)ws_size;
    const int*   t1    = (const int*)d_in[0];
    const int*   t2    = (const int*)d_in[1];
    const float* emb   = (const float*)d_in[2];
    const float* wih_f = (const float*)d_in[3];
    const float* whh_f = (const float*)d_in[4];
    const float* bih_f = (const float*)d_in[5];
    const float* bhh_f = (const float*)d_in[6];
    const float* wih_b = (const float*)d_in[7];
    const float* whh_b = (const float*)d_in[8];
    const float* bih_b = (const float*)d_in[9];
    const float* bhh_b = (const float*)d_in[10];
    float* out = (float*)d_out;

    char* ws = (char*)d_ws;
    size_t off = 0;
    auto carve = [&](size_t bytes) -> void* {
        void* p = ws + off;
        off = (off + bytes + 255) & ~(size_t)255;
        return p;
    };
    // o1 region doubles as bf16 A (same 16.8 MB size; A dead before scan writes o1)
    float*  o1   = (float*)carve(sizeof(float)*(size_t)L_SEQ*NB*DDIM);
    float*  o2   = (float*)carve(sizeof(float)*(size_t)L_SEQ*NB*DDIM);
    bf16_t* whhB = (bf16_t*)carve(sizeof(bf16_t)*2*1024*HID);
    bf16_t* Bw   = (bf16_t*)carve(sizeof(bf16_t)*(size_t)NCOL*EMBD);
    float*  bias = (float*)carve(sizeof(float)*NCOL);
    float*  mp1  = (float*)carve(sizeof(float)*NB*DDIM);
    float*  xgb  = (float*)carve(sizeof(float)*(size_t)MTOT*NCOL);   // 134 MB
    bf16_t* A    = (bf16_t*)o1;

    hipLaunchKernelGGL(k_pack_a,    dim3(4096), dim3(256), 0, stream, t1, t2, emb, A);
    hipLaunchKernelGGL(k_pack_b,    dim3(512),  dim3(256), 0, stream, wih_f, wih_b, Bw);
    hipLaunchKernelGGL(k_pack_whh,  dim3(256),  dim3(256), 0, stream, whh_f, whh_b, whhB);
    hipLaunchKernelGGL(k_pack_bias, dim3(8),    dim3(256), 0, stream,
                       bih_f, bhh_f, bih_b, bhh_b, bias);

    hipLaunchKernelGGL(xg_gemm2, dim3(16, 128), dim3(256), 0, stream, A, Bw, bias, xgb);

    hipLaunchKernelGGL(lstm_scan2, dim3(16, 2), dim3(512), 0, stream, whhB, xgb, o1, o2);

    hipLaunchKernelGGL(k_mp1,    dim3(256), dim3(256), 0, stream, o1, mp1);
    hipLaunchKernelGGL(k_att,    dim3(128), dim3(256), 0, stream, o2, mp1, out);
    hipLaunchKernelGGL(k_common, dim3(128), dim3(256), 0, stream,
                       t1, t2, o1, o2, out + NB, out + NB + NB*DDIM);
}